// Round 10
// baseline (366.700 us; speedup 1.0000x reference)
//
#include <hip/hip_runtime.h>
#include <math.h>

#define IMG 1024
#define NXT 26              // x tiles: 40 output cols each (26*40=1040 >= 1024)
#define NYT 16              // y tiles: 64 output rows each

// Register-resident wave tile, R10: in-place fused erode+dilate.
//  - lane = column (64 cols), rows packed 2/VGPR fp16x2: S[44] single buffer.
//  - erode computed ascending with rolling window; dilate of pair p emitted at
//    k=p+1 (needs e[p-1],e[p],e[p+1]) reading original S[p] BEFORE S[p]<-e[p].
//    Kills the 44-reg ping-pong buffer: natural VGPR ~110.
//  - __launch_bounds__(128,8): VGPR cap = 131072/(128*8) = 128 (R1 pinned the
//    formula) -> 4 waves/SIMD, all 13 waves/CU resident in ONE round.
//  - j-loop ROLLED (#pragma unroll 1): body ~6KB, fits 32KB L1I (R9's 84KB
//    unrolled body thrashed I-fetch with ~1 wave/SIMD to hide it).
//  - one-time OOB seed for erode (min-filter monotone + grid-convex rect ==
//    per-step +inf pad); dilate masks inputs per step (BND waves only).
typedef _Float16 h2 __attribute__((ext_vector_type(2)));
union UH { unsigned u; h2 h; };
__device__ __forceinline__ h2 u2h(unsigned u){ UH x; x.u=u; return x.h; }
__device__ __forceinline__ unsigned h2u(h2 h){ UH x; x.h=h; return x.u; }
__device__ __forceinline__ h2 pmin(h2 a,h2 b){ return __builtin_elementwise_min(a,b); }
__device__ __forceinline__ h2 pmax(h2 a,h2 b){ return __builtin_elementwise_max(a,b); }
// {.x = lo_src.y, .y = hi_src.x} : row-pair shift helper (v_alignbit)
__device__ __forceinline__ h2 funnel(h2 hi_src,h2 lo_src){ return u2h((h2u(lo_src)>>16)|(h2u(hi_src)<<16)); }
// full-wave lane shifts (GFX9 DPP wave_shr/wave_shl, cross 16-lane rows);
// boundary lane takes old (bound_ctrl=false)
__device__ __forceinline__ unsigned wshr(unsigned old_,unsigned src){
  return (unsigned)__builtin_amdgcn_update_dpp((int)old_,(int)src,0x138,0xF,0xF,false);
}
__device__ __forceinline__ unsigned wshl(unsigned old_,unsigned src){
  return (unsigned)__builtin_amdgcn_update_dpp((int)old_,(int)src,0x130,0xF,0xF,false);
}
__device__ __forceinline__ float sigmoidf(float x){ return 1.0f/(1.0f+__expf(-x)); }

template<bool BND>
__device__ __forceinline__ void wave_tile(const float* __restrict__ pb, const int* __restrict__ tb,
                                          int or0, int oc0, int lane, float (&s)[7]){
  const int c  = oc0 - 12 + lane;
  const bool cv = (unsigned)c < (unsigned)IMG;
  const int cc = BND ? (c<0?0:(c>IMG-1?IMG-1:c)) : c;
  int lo=0, hi=88;
  unsigned pm0=~0u, pm1=~0u, pm2=0x00FFFFFFu;   // dilate-valid masks (bits in-image)
  if (BND){
    lo = (or0<0)? -or0 : 0;                      // valid local rows [lo,hi), both even
    hi = (IMG-or0<88)? IMG-or0 : 88;
    unsigned m[3];
    #pragma unroll
    for (int w=0;w<3;++w){
      int l = lo-32*w; l=l<0?0:(l>32?32:l);
      int h = hi-32*w; h=h<0?0:(h>32?32:h);
      unsigned mm=0;
      if (h>l){ unsigned top=(h>=32)?~0u:((1u<<h)-1u); unsigned bot=(l<=0)?0u:((1u<<l)-1u); mm=top&~bot; }
      m[w]=mm;
    }
    unsigned cin = cv?0u:~0u;
    pm0=m[0]&~cin; pm1=m[1]&~cin; pm2=m[2]&~cin;
  }
  const h2 twos  = {(_Float16)2.0f,(_Float16)2.0f};
  const h2 zerov = {(_Float16)0.0f,(_Float16)0.0f};

  h2 S[44], skel[32];
  unsigned t0=0,t1=0,t2=0xFF000000u;             // pseudo rows 88..95 erode-neutral 1
  // ---- stage (88 rows; one row per load instr = 256B coalesced across lanes) ----
  #pragma unroll
  for (int k=0;k<44;++k){
    int r0=or0+2*k, r1=r0+1;
    int g0 = BND ? (r0<0?0:(r0>IMG-1?IMG-1:r0)) : r0;
    int g1 = BND ? (r1<0?0:(r1>IMG-1?IMG-1:r1)) : r1;
    float x0 = pb[(long)g0*IMG+cc];
    float x1 = pb[(long)g1*IMG+cc];
    int v0 = tb[(long)g0*IMG+cc];
    int v1 = tb[(long)g1*IMG+cc];
    h2 hh; hh.x=(_Float16)sigmoidf(x0); hh.y=(_Float16)sigmoidf(x1);
    if (BND){
      bool bad = (2*k < lo) || (2*k >= hi);      // pair-uniform (lo,hi even)
      hh = (bad || !cv) ? twos : hh;             // one-time +inf seed
    }
    S[k]=hh;
    unsigned add = ((unsigned)(v0!=0)<<((2*k)&31)) | ((unsigned)(v1!=0)<<((2*k+1)&31));
    if (k<16) t0|=add; else if (k<32) t1|=add; else t2|=add;
  }
  if (BND){ t0 |= ~pm0; t1 |= ~pm1; t2 |= ~pm2; }  // one-time erode-neutral 1 seed
  const unsigned q0=t0,q1=t1,q2=t2;
  unsigned sk0=0,sk1=0,sk2=0;
  #pragma unroll
  for (int i=0;i<32;++i) skel[i]=zerov;

  #pragma unroll 1
  for (int j=0;j<11;++j){
    // ---- targ erode + dilate + skel_t bits ----
    {
      unsigned o0=t0,o1=t1,o2=t2;
      unsigned U0=(t0<<1)|1u,       U1=(t1<<1)|(t0>>31), U2=(t2<<1)|(t1>>31);
      unsigned D0=(t0>>1)|(t1<<31), D1=(t1>>1)|(t2<<31), D2=(t2>>1)|0x80000000u;
      unsigned L0=wshr(~0u,t0), L1=wshr(~0u,t1), L2=wshr(~0u,t2);
      unsigned R0=wshl(~0u,t0), R1=wshl(~0u,t1), R2=wshl(~0u,t2);
      t0 &= U0&D0&L0&R0; t1 &= U1&D1&L1&R1; t2 &= U2&D2&L2&R2;
      unsigned g0=t0, g1=t1, g2=t2;
      if (BND){ g0&=pm0; g1&=pm1; g2&=pm2; }     // dilate needs masked-to-0 inputs
      unsigned V0 = g0|(g0<<1)|((g0>>1)|(g1<<31));
      unsigned V1 = g1|((g1<<1)|(g0>>31))|((g1>>1)|(g2<<31));
      unsigned V2 = g2|((g2<<1)|(g1>>31))|(g2>>1);
      unsigned d0 = V0|wshr(0u,V0)|wshl(0u,V0);
      unsigned d1 = V1|wshr(0u,V1)|wshl(0u,V1);
      unsigned d2 = V2|wshr(0u,V2)|wshl(0u,V2);
      sk0 |= o0&~d0; sk1 |= o1&~d1; sk2 |= o2&~d2;
    }
    // ---- fused in-place pred erode (5-cross min) + 3x3 dilate + skel ----
    {
      h2 pf = funnel(S[0], twos);                // su for k=0 (rows -1,0)
      h2 est1 = zerov;                           // raw e[k-1] (store-back)
      h2 dm1  = zerov;                           // masked e[k-1] (dilate input)
      h2 fprev= zerov;                           // fU(k-1) = funnel(e[k-1]m, e[k-2]m)
      #pragma unroll
      for (int k=0;k<44;++k){
        h2 mc = S[k];
        h2 mn = (k<43)? S[k+1] : twos;
        h2 sd = funnel(mn, mc);
        h2 v3 = pmin(pmin(pf,sd), mc);
        pf = sd;
        h2 l3 = u2h(wshr(h2u(twos), h2u(mc)));
        h2 r3 = u2h(wshl(h2u(twos), h2u(mc)));
        h2 ek = pmin(pmin(l3,r3), v3);           // e[k] = erode pair k
        h2 ekm = ek;
        if (BND){
          bool bad = (2*k < lo) || (2*k >= hi);
          ekm = (bad || !cv) ? zerov : ek;       // max-filter: OOB -> 0 each step
        }
        h2 fcur = zerov;
        if (k>=6) fcur = funnel(ekm, dm1);       // fU(k) = fD(k-1)
        if (k>=7 && k<=38){
          const int p = k-1;                     // output pairs 6..37
          h2 vm = pmax(pmax(fprev,fcur), dm1);   // vertical max3 of e at pair p
          h2 lm = u2h(wshr(0u, h2u(vm)));
          h2 rr = u2h(wshl(0u, h2u(vm)));
          h2 hm = pmax(pmax(lm,rr), vm);         // 3x3 dilate
          h2 d  = pmax(S[p]-hm, zerov);          // original S[p] (not yet stored)
          h2 x2 = d - skel[p-6]*d;
          skel[p-6] = skel[p-6] + pmax(x2, zerov);
        }
        if (k>=1) S[k-1] = est1;                 // store e[k-1] (all readers done)
        est1 = ek; dm1 = ekm; fprev = fcur;
      }
      S[43] = est1;
    }
  }

  // ---- sums; pred reloaded (output rows always in-image) ----
  #pragma unroll
  for (int k2=0;k2<7;++k2) s[k2]=0.f;
  #pragma unroll
  for (int i=0;i<32;++i){
    int k=i+6;
    long r0 = (long)(or0+2*k);
    float x0 = pb[r0*IMG+cc], x1 = pb[(r0+1)*IMG+cc];
    float p0 = sigmoidf(x0), p1 = sigmoidf(x1);
    int b=(2*k)&31, w=(2*k)>>5;
    unsigned qw = (w==0)?q0:((w==1)?q1:q2);
    unsigned sw = (w==0)?sk0:((w==1)?sk1:sk2);
    float a0=(float)skel[i].x, a1=(float)skel[i].y;
    float tb0=(float)((qw>>b)&1u), tb1=(float)((qw>>(b+1))&1u);
    float sb0=(float)((sw>>b)&1u), sb1=(float)((sw>>(b+1))&1u);
    s[0]+=a0+a1;          s[1]+=a0*tb0+a1*tb1;
    s[2]+=sb0+sb1;        s[3]+=sb0*p0+sb1*p1;
    s[4]+=p0*tb0+p1*tb1;  s[5]+=p0+p1;  s[6]+=tb0+tb1;
  }
}

__global__ __launch_bounds__(128,8)
void cl_dice_main(const float* __restrict__ pred, const int* __restrict__ targ,
                  float* __restrict__ ws){
  __shared__ float red[2][8];
  const int tid=threadIdx.x, lane=tid&63, wv=tid>>6;
  const int wid = blockIdx.x*2 + wv;
  const int tx = wid % NXT; const int tt = wid/NXT;
  const int ty = tt % NYT;  const int z  = tt/NYT;
  const long base = (long)z*IMG*IMG;
  const int or0 = ty*64-12, oc0 = tx*40;
  const bool bnd = (tx==0)|(tx==NXT-1)|(ty==0)|(ty==NYT-1);
  float s[7];
  if (!bnd) wave_tile<false>(pred+base, targ+base, or0, oc0, lane, s);
  else      wave_tile<true >(pred+base, targ+base, or0, oc0, lane, s);
  const int c = oc0-12+lane;
  const float msk = ((lane>=12)&&(lane<=51)&&(c<IMG)) ? 1.f : 0.f;
  #pragma unroll
  for (int k=0;k<7;++k){
    float v = s[k]*msk;
    v+=__shfl_down(v,32); v+=__shfl_down(v,16); v+=__shfl_down(v,8);
    v+=__shfl_down(v,4);  v+=__shfl_down(v,2);  v+=__shfl_down(v,1);
    if (lane==0) red[wv][k]=v;
  }
  __syncthreads();
  if (tid<7) ws[blockIdx.x*8+tid] = red[0][tid]+red[1][tid];
}

__global__ __launch_bounds__(256)
void cl_dice_finalize(const float* __restrict__ ws, float* __restrict__ out, int nblk) {
  __shared__ float red[4][8];
  int tid = threadIdx.x;
  float acc[7] = {0,0,0,0,0,0,0};
  for (int i=tid; i<nblk; i+=256) {
    #pragma unroll
    for (int k=0;k<7;++k) acc[k] += ws[i*8 + k];
  }
  #pragma unroll
  for (int k=0;k<7;++k){
    float v = acc[k];
    v += __shfl_down(v,32); v += __shfl_down(v,16); v += __shfl_down(v,8);
    v += __shfl_down(v,4);  v += __shfl_down(v,2);  v += __shfl_down(v,1);
    if ((tid & 63) == 0) red[tid>>6][k] = v;
  }
  __syncthreads();
  if (tid == 0) {
    float t0[7];
    #pragma unroll
    for (int k=0;k<7;++k) t0[k] = red[0][k] + red[1][k] + red[2][k] + red[3][k];
    float sum_sp = t0[0], sum_spt = t0[1], sum_st = t0[2], sum_stp = t0[3];
    float inter  = t0[4], sum_p   = t0[5], sum_t  = t0[6];
    float tprec = (sum_spt + 1.0f) / (sum_sp + 1.0f);
    float tsens = (sum_stp + 1.0f) / (sum_st + 1.0f);
    float cl    = 2.0f * tprec * tsens / (tprec + tsens + 1e-7f);
    float dice  = (2.0f * inter + 1.0f) / (sum_p + sum_t + 1.0f);
    out[0] = 1.0f - 0.5f * (dice + cl);
  }
}

extern "C" void kernel_launch(void* const* d_in, const int* in_sizes, int n_in,
                              void* d_out, int out_size, void* d_ws, size_t ws_size,
                              hipStream_t stream) {
  const float* pred = (const float*)d_in[0];
  const int*   targ = (const int*)d_in[1];
  float* ws  = (float*)d_ws;
  float* out = (float*)d_out;

  const int B = in_sizes[0] / (IMG * IMG);     // 8
  const int nw   = NXT*NYT*B;                  // 3328 waves
  const int nblk = nw / 2;                     // 1664 blocks x 128 threads
  cl_dice_main<<<nblk, 128, 0, stream>>>(pred, targ, ws);
  cl_dice_finalize<<<1, 256, 0, stream>>>(ws, out, nblk);
}

// Round 11
// 228.117 us; speedup vs baseline: 1.6075x; 1.6075x over previous
//
#include <hip/hip_runtime.h>
#include <math.h>

#define IMG 1024
#define NXT 26              // x tiles: 40 output cols each (26*40=1040 >= 1024)
#define NYT 16              // y tiles: 64 output rows each

// Register-resident wave tile, R11 = R10 fused in-place design with the
// CORRECT launch-bounds cap. Empirical gfx950 mapping (R1/R2/R5/R9/R10):
// VGPR cap = 256 / arg2 (block-size independent): arg2=8 -> 32 (R10 spilled
// 557MB), arg2=4 -> 64, arg2=1 -> uncapped (R9: 140 -> 2 waves/SIMD).
// arg2=2 -> cap 128 = the m69 occupancy step (<=128 -> 4 waves/SIMD).
// Natural need after killing the ping-pong buffer ~100-115 -> spill-free.
// 3328 waves vs 4096 resident slots -> full residency, one scheduling round.
typedef _Float16 h2 __attribute__((ext_vector_type(2)));
union UH { unsigned u; h2 h; };
__device__ __forceinline__ h2 u2h(unsigned u){ UH x; x.u=u; return x.h; }
__device__ __forceinline__ unsigned h2u(h2 h){ UH x; x.h=h; return x.u; }
__device__ __forceinline__ h2 pmin(h2 a,h2 b){ return __builtin_elementwise_min(a,b); }
__device__ __forceinline__ h2 pmax(h2 a,h2 b){ return __builtin_elementwise_max(a,b); }
// {.x = lo_src.y, .y = hi_src.x} : row-pair shift helper (v_alignbit)
__device__ __forceinline__ h2 funnel(h2 hi_src,h2 lo_src){ return u2h((h2u(lo_src)>>16)|(h2u(hi_src)<<16)); }
// full-wave lane shifts (GFX9 DPP wave_shr/wave_shl, cross 16-lane rows);
// boundary lane takes old (bound_ctrl=false)
__device__ __forceinline__ unsigned wshr(unsigned old_,unsigned src){
  return (unsigned)__builtin_amdgcn_update_dpp((int)old_,(int)src,0x138,0xF,0xF,false);
}
__device__ __forceinline__ unsigned wshl(unsigned old_,unsigned src){
  return (unsigned)__builtin_amdgcn_update_dpp((int)old_,(int)src,0x130,0xF,0xF,false);
}
__device__ __forceinline__ float sigmoidf(float x){ return 1.0f/(1.0f+__expf(-x)); }

template<bool BND>
__device__ __forceinline__ void wave_tile(const float* __restrict__ pb, const int* __restrict__ tb,
                                          int or0, int oc0, int lane, float (&s)[7]){
  const int c  = oc0 - 12 + lane;
  const bool cv = (unsigned)c < (unsigned)IMG;
  const int cc = BND ? (c<0?0:(c>IMG-1?IMG-1:c)) : c;
  int lo=0, hi=88;
  unsigned pm0=~0u, pm1=~0u, pm2=0x00FFFFFFu;   // dilate-valid masks (bits in-image)
  if (BND){
    lo = (or0<0)? -or0 : 0;                      // valid local rows [lo,hi), both even
    hi = (IMG-or0<88)? IMG-or0 : 88;
    unsigned m[3];
    #pragma unroll
    for (int w=0;w<3;++w){
      int l = lo-32*w; l=l<0?0:(l>32?32:l);
      int h = hi-32*w; h=h<0?0:(h>32?32:h);
      unsigned mm=0;
      if (h>l){ unsigned top=(h>=32)?~0u:((1u<<h)-1u); unsigned bot=(l<=0)?0u:((1u<<l)-1u); mm=top&~bot; }
      m[w]=mm;
    }
    unsigned cin = cv?0u:~0u;
    pm0=m[0]&~cin; pm1=m[1]&~cin; pm2=m[2]&~cin;
  }
  const h2 twos  = {(_Float16)2.0f,(_Float16)2.0f};
  const h2 zerov = {(_Float16)0.0f,(_Float16)0.0f};

  h2 S[44], skel[32];
  unsigned t0=0,t1=0,t2=0xFF000000u;             // pseudo rows 88..95 erode-neutral 1
  // ---- stage (88 rows; one row per load instr = 256B coalesced across lanes) ----
  #pragma unroll
  for (int k=0;k<44;++k){
    int r0=or0+2*k, r1=r0+1;
    int g0 = BND ? (r0<0?0:(r0>IMG-1?IMG-1:r0)) : r0;
    int g1 = BND ? (r1<0?0:(r1>IMG-1?IMG-1:r1)) : r1;
    float x0 = pb[(long)g0*IMG+cc];
    float x1 = pb[(long)g1*IMG+cc];
    int v0 = tb[(long)g0*IMG+cc];
    int v1 = tb[(long)g1*IMG+cc];
    h2 hh; hh.x=(_Float16)sigmoidf(x0); hh.y=(_Float16)sigmoidf(x1);
    if (BND){
      bool bad = (2*k < lo) || (2*k >= hi);      // pair-uniform (lo,hi even)
      hh = (bad || !cv) ? twos : hh;             // one-time +inf seed
    }
    S[k]=hh;
    unsigned add = ((unsigned)(v0!=0)<<((2*k)&31)) | ((unsigned)(v1!=0)<<((2*k+1)&31));
    if (k<16) t0|=add; else if (k<32) t1|=add; else t2|=add;
  }
  if (BND){ t0 |= ~pm0; t1 |= ~pm1; t2 |= ~pm2; }  // one-time erode-neutral 1 seed
  const unsigned q0=t0,q1=t1,q2=t2;
  unsigned sk0=0,sk1=0,sk2=0;
  #pragma unroll
  for (int i=0;i<32;++i) skel[i]=zerov;

  #pragma unroll 1
  for (int j=0;j<11;++j){
    // ---- targ erode + dilate + skel_t bits ----
    {
      unsigned o0=t0,o1=t1,o2=t2;
      unsigned U0=(t0<<1)|1u,       U1=(t1<<1)|(t0>>31), U2=(t2<<1)|(t1>>31);
      unsigned D0=(t0>>1)|(t1<<31), D1=(t1>>1)|(t2<<31), D2=(t2>>1)|0x80000000u;
      unsigned L0=wshr(~0u,t0), L1=wshr(~0u,t1), L2=wshr(~0u,t2);
      unsigned R0=wshl(~0u,t0), R1=wshl(~0u,t1), R2=wshl(~0u,t2);
      t0 &= U0&D0&L0&R0; t1 &= U1&D1&L1&R1; t2 &= U2&D2&L2&R2;
      unsigned g0=t0, g1=t1, g2=t2;
      if (BND){ g0&=pm0; g1&=pm1; g2&=pm2; }     // dilate needs masked-to-0 inputs
      unsigned V0 = g0|(g0<<1)|((g0>>1)|(g1<<31));
      unsigned V1 = g1|((g1<<1)|(g0>>31))|((g1>>1)|(g2<<31));
      unsigned V2 = g2|((g2<<1)|(g1>>31))|(g2>>1);
      unsigned d0 = V0|wshr(0u,V0)|wshl(0u,V0);
      unsigned d1 = V1|wshr(0u,V1)|wshl(0u,V1);
      unsigned d2 = V2|wshr(0u,V2)|wshl(0u,V2);
      sk0 |= o0&~d0; sk1 |= o1&~d1; sk2 |= o2&~d2;
    }
    // ---- fused in-place pred erode (5-cross min) + 3x3 dilate + skel ----
    {
      h2 pf = funnel(S[0], twos);                // su for k=0 (rows -1,0)
      h2 est1 = zerov;                           // raw e[k-1] (store-back)
      h2 dm1  = zerov;                           // masked e[k-1] (dilate input)
      h2 fprev= zerov;                           // fU(k-1) = funnel(e[k-1]m, e[k-2]m)
      #pragma unroll
      for (int k=0;k<44;++k){
        h2 mc = S[k];
        h2 mn = (k<43)? S[k+1] : twos;
        h2 sd = funnel(mn, mc);
        h2 v3 = pmin(pmin(pf,sd), mc);
        pf = sd;
        h2 l3 = u2h(wshr(h2u(twos), h2u(mc)));
        h2 r3 = u2h(wshl(h2u(twos), h2u(mc)));
        h2 ek = pmin(pmin(l3,r3), v3);           // e[k] = erode pair k
        h2 ekm = ek;
        if (BND){
          bool bad = (2*k < lo) || (2*k >= hi);
          ekm = (bad || !cv) ? zerov : ek;       // max-filter: OOB -> 0 each step
        }
        h2 fcur = zerov;
        if (k>=6) fcur = funnel(ekm, dm1);       // fU(k) = fD(k-1)
        if (k>=7 && k<=38){
          const int p = k-1;                     // output pairs 6..37
          h2 vm = pmax(pmax(fprev,fcur), dm1);   // vertical max3 of e at pair p
          h2 lm = u2h(wshr(0u, h2u(vm)));
          h2 rr = u2h(wshl(0u, h2u(vm)));
          h2 hm = pmax(pmax(lm,rr), vm);         // 3x3 dilate
          h2 d  = pmax(S[p]-hm, zerov);          // original S[p] (not yet stored)
          h2 x2 = d - skel[p-6]*d;
          skel[p-6] = skel[p-6] + pmax(x2, zerov);
        }
        if (k>=1) S[k-1] = est1;                 // store e[k-1] (all readers done)
        est1 = ek; dm1 = ekm; fprev = fcur;
      }
      S[43] = est1;
    }
  }

  // ---- sums; pred reloaded (output rows always in-image) ----
  #pragma unroll
  for (int k2=0;k2<7;++k2) s[k2]=0.f;
  #pragma unroll
  for (int i=0;i<32;++i){
    int k=i+6;
    long r0 = (long)(or0+2*k);
    float x0 = pb[r0*IMG+cc], x1 = pb[(r0+1)*IMG+cc];
    float p0 = sigmoidf(x0), p1 = sigmoidf(x1);
    int b=(2*k)&31, w=(2*k)>>5;
    unsigned qw = (w==0)?q0:((w==1)?q1:q2);
    unsigned sw = (w==0)?sk0:((w==1)?sk1:sk2);
    float a0=(float)skel[i].x, a1=(float)skel[i].y;
    float tb0=(float)((qw>>b)&1u), tb1=(float)((qw>>(b+1))&1u);
    float sb0=(float)((sw>>b)&1u), sb1=(float)((sw>>(b+1))&1u);
    s[0]+=a0+a1;          s[1]+=a0*tb0+a1*tb1;
    s[2]+=sb0+sb1;        s[3]+=sb0*p0+sb1*p1;
    s[4]+=p0*tb0+p1*tb1;  s[5]+=p0+p1;  s[6]+=tb0+tb1;
  }
}

__global__ __launch_bounds__(128,2)
void cl_dice_main(const float* __restrict__ pred, const int* __restrict__ targ,
                  float* __restrict__ ws){
  __shared__ float red[2][8];
  const int tid=threadIdx.x, lane=tid&63, wv=tid>>6;
  const int wid = blockIdx.x*2 + wv;
  const int tx = wid % NXT; const int tt = wid/NXT;
  const int ty = tt % NYT;  const int z  = tt/NYT;
  const long base = (long)z*IMG*IMG;
  const int or0 = ty*64-12, oc0 = tx*40;
  const bool bnd = (tx==0)|(tx==NXT-1)|(ty==0)|(ty==NYT-1);
  float s[7];
  if (!bnd) wave_tile<false>(pred+base, targ+base, or0, oc0, lane, s);
  else      wave_tile<true >(pred+base, targ+base, or0, oc0, lane, s);
  const int c = oc0-12+lane;
  const float msk = ((lane>=12)&&(lane<=51)&&(c<IMG)) ? 1.f : 0.f;
  #pragma unroll
  for (int k=0;k<7;++k){
    float v = s[k]*msk;
    v+=__shfl_down(v,32); v+=__shfl_down(v,16); v+=__shfl_down(v,8);
    v+=__shfl_down(v,4);  v+=__shfl_down(v,2);  v+=__shfl_down(v,1);
    if (lane==0) red[wv][k]=v;
  }
  __syncthreads();
  if (tid<7) ws[blockIdx.x*8+tid] = red[0][tid]+red[1][tid];
}

__global__ __launch_bounds__(256)
void cl_dice_finalize(const float* __restrict__ ws, float* __restrict__ out, int nblk) {
  __shared__ float red[4][8];
  int tid = threadIdx.x;
  float acc[7] = {0,0,0,0,0,0,0};
  for (int i=tid; i<nblk; i+=256) {
    #pragma unroll
    for (int k=0;k<7;++k) acc[k] += ws[i*8 + k];
  }
  #pragma unroll
  for (int k=0;k<7;++k){
    float v = acc[k];
    v += __shfl_down(v,32); v += __shfl_down(v,16); v += __shfl_down(v,8);
    v += __shfl_down(v,4);  v += __shfl_down(v,2);  v += __shfl_down(v,1);
    if ((tid & 63) == 0) red[tid>>6][k] = v;
  }
  __syncthreads();
  if (tid == 0) {
    float t0[7];
    #pragma unroll
    for (int k=0;k<7;++k) t0[k] = red[0][k] + red[1][k] + red[2][k] + red[3][k];
    float sum_sp = t0[0], sum_spt = t0[1], sum_st = t0[2], sum_stp = t0[3];
    float inter  = t0[4], sum_p   = t0[5], sum_t  = t0[6];
    float tprec = (sum_spt + 1.0f) / (sum_sp + 1.0f);
    float tsens = (sum_stp + 1.0f) / (sum_st + 1.0f);
    float cl    = 2.0f * tprec * tsens / (tprec + tsens + 1e-7f);
    float dice  = (2.0f * inter + 1.0f) / (sum_p + sum_t + 1.0f);
    out[0] = 1.0f - 0.5f * (dice + cl);
  }
}

extern "C" void kernel_launch(void* const* d_in, const int* in_sizes, int n_in,
                              void* d_out, int out_size, void* d_ws, size_t ws_size,
                              hipStream_t stream) {
  const float* pred = (const float*)d_in[0];
  const int*   targ = (const int*)d_in[1];
  float* ws  = (float*)d_ws;
  float* out = (float*)d_out;

  const int B = in_sizes[0] / (IMG * IMG);     // 8
  const int nw   = NXT*NYT*B;                  // 3328 waves
  const int nblk = nw / 2;                     // 1664 blocks x 128 threads
  cl_dice_main<<<nblk, 128, 0, stream>>>(pred, targ, ws);
  cl_dice_finalize<<<1, 256, 0, stream>>>(ws, out, nblk);
}